// Round 9
// baseline (389.060 us; speedup 1.0000x reference)
//
#include <hip/hip_runtime.h>
#include <hip/hip_bf16.h>

// Problem constants (BLoraLinear): T=8192, D_IN=4096, D_OUT=4096, R=16, M=2, S=8
#define T_TOK 8192
#define DIN   4096
#define DOUT  4096
#define RANK  16
#define NMOD  2
#define NSEG  8

typedef __attribute__((ext_vector_type(8))) short bf16x8;
typedef __attribute__((ext_vector_type(8))) unsigned short u16x8;
typedef __attribute__((ext_vector_type(4))) float f32x4;

__device__ inline unsigned short f2bf(float f) {
    union { float f; unsigned u; } v; v.f = f;
    unsigned r = v.u + 0x7FFFu + ((v.u >> 16) & 1u);   // RNE
    return (unsigned short)(r >> 16);
}

__device__ inline void gload_lds16(const void* g, void* l) {
    __builtin_amdgcn_global_load_lds(
        (const __attribute__((address_space(1))) void*)g,
        (__attribute__((address_space(3))) void*)l, 16, 0, 0);
}

// ---- fp32 -> bf16 cast: x -> linear xb; W -> MFMA-fragment-tiled wbt --------
// wbt block (ct,kt) = 16 cols x 32 k, 1 KB: ushort ofs = (ct*128+kt)*512
//   + c*32 + lk*8 + j   <-  W[ct*16+c][kt*32+lk*8+j]
// One wave's B-frag load (lane: c=l15, lk) covers the block contiguously.
__global__ void cast2_bf16_kernel(const float* __restrict__ sa,
                                  unsigned short* __restrict__ da, int n8a,
                                  const float* __restrict__ sb,
                                  unsigned short* __restrict__ db, int n8b) {
    int i = blockIdx.x * blockDim.x + threadIdx.x;
    if (i < n8a) {
        size_t j = (size_t)i;
        const float4* s4 = (const float4*)sa;
        float4 a = s4[2 * j], b = s4[2 * j + 1];
        u16x8 o;
        o[0] = f2bf(a.x); o[1] = f2bf(a.y); o[2] = f2bf(a.z); o[3] = f2bf(a.w);
        o[4] = f2bf(b.x); o[5] = f2bf(b.y); o[6] = f2bf(b.z); o[7] = f2bf(b.w);
        *(u16x8*)(da + 8 * j) = o;
    } else if (i < n8a + n8b) {
        size_t j = (size_t)(i - n8a);
        const float4* s4 = (const float4*)sb;
        float4 a = s4[2 * j], b = s4[2 * j + 1];
        u16x8 o;
        o[0] = f2bf(a.x); o[1] = f2bf(a.y); o[2] = f2bf(a.z); o[3] = f2bf(a.w);
        o[4] = f2bf(b.x); o[5] = f2bf(b.y); o[6] = f2bf(b.z); o[7] = f2bf(b.w);
        int row = (int)(j >> 9);            // DIN/8 = 512
        int kc  = ((int)j & 511) << 3;
        int ct = row >> 4, c = row & 15, kt = kc >> 5, lk = (kc >> 3) & 3;
        size_t dst = ((size_t)(ct * 128 + kt) << 9) + c * 32 + lk * 8;
        *(u16x8*)(db + dst) = o;
    }
}

// ---------- At[s][m*16+r][d] = lora_A[m][s][d][r]  (bf16) --------------------
__global__ void prep_A_kernel(const float* __restrict__ A,
                              unsigned short* __restrict__ At) {
    int idx = blockIdx.x * 256 + threadIdx.x;     // NSEG*32*DIN total
    int d   = idx & (DIN - 1);
    int smr = idx >> 12;
    int s   = smr >> 5, mr = smr & 31;
    int m   = mr >> 4,  r  = mr & 15;
    float v = A[(((size_t)(m * NSEG + s) * DIN) + d) * RANK + r];
    At[idx] = f2bf(v);
}

// ---------- Bt[s][o][m*16+r] = lora_B[m][s][r][o]  (bf16) --------------------
__global__ void prep_B_kernel(const float* __restrict__ B,
                              unsigned short* __restrict__ Bt) {
    int o  = blockIdx.x * 256 + threadIdx.x;      // NSEG*DOUT total
    int s  = o >> 12;
    int oc = o & (DOUT - 1);
    unsigned short tmp[32];
    for (int m = 0; m < NMOD; ++m)
        for (int r = 0; r < RANK; ++r)
            tmp[m * 16 + r] =
                f2bf(B[(((size_t)(m * NSEG + s) * RANK) + r) * DOUT + oc]);
    for (int k = 0; k < 4; ++k) {
        u16x8 v;
        for (int j = 0; j < 8; ++j) v[j] = tmp[k * 8 + j];
        *(u16x8*)(Bt + (size_t)o * 32 + k * 8) = v;
    }
}

// ---------- u partials: Pu[ky][t][mr] = sum_{k in split} x[t,k]*At[s(t)][mr][k]
__global__ __launch_bounds__(64) void u_gemm_kernel(
    const unsigned short* __restrict__ xb, const unsigned short* __restrict__ At,
    const int* __restrict__ cu, float* __restrict__ Pu) {
    int tile = blockIdx.x;          // 0..255
    int ky   = blockIdx.y;          // 0..3
    int lane = threadIdx.x;
    int l15  = lane & 15, lk = lane >> 4;
    int t0   = tile * 32;
    f32x4 acc[2][2] = {};
    bf16x8 zero = {};
    for (int s = 0; s < NSEG; ++s) {
        int lo = cu[s], hi = cu[s + 1];
        if (hi <= t0 || lo >= t0 + 32) continue;
        const unsigned short* atb = At + (size_t)(s * 32) * DIN;
        for (int kt = 0; kt < 32; ++kt) {
            int k0 = ky * 1024 + kt * 32 + lk * 8;
            bf16x8 a[2], b[2];
            for (int mi = 0; mi < 2; ++mi) {
                int row = t0 + mi * 16 + l15;
                bf16x8 av = *(const bf16x8*)(xb + (size_t)row * DIN + k0);
                a[mi] = (row >= lo && row < hi) ? av : zero;
            }
            for (int ni = 0; ni < 2; ++ni) {
                int mr = ni * 16 + l15;
                b[ni] = *(const bf16x8*)(atb + (size_t)mr * DIN + k0);
            }
            for (int mi = 0; mi < 2; ++mi)
                for (int ni = 0; ni < 2; ++ni)
                    acc[mi][ni] = __builtin_amdgcn_mfma_f32_16x16x32_bf16(
                        a[mi], b[ni], acc[mi][ni], 0, 0, 0);
        }
    }
    for (int mi = 0; mi < 2; ++mi)
        for (int ni = 0; ni < 2; ++ni)
            for (int j = 0; j < 4; ++j) {
                int t  = t0 + mi * 16 + lk * 4 + j;
                int mr = ni * 16 + l15;
                Pu[((size_t)ky * T_TOK + t) * 32 + mr] = acc[mi][ni][j];
            }
}

// ---------- reduce 4 K-split partials -> ub bf16 [T][32] ---------------------
__global__ void reduce_u_kernel(const float* __restrict__ Pu,
                                unsigned short* __restrict__ ub) {
    int idx = blockIdx.x * 256 + threadIdx.x;   // T_TOK*32
    const size_t STRIDE = (size_t)T_TOK * 32;
    float s = Pu[idx] + Pu[idx + STRIDE] + Pu[idx + 2 * STRIDE] + Pu[idx + 3 * STRIDE];
    ub[idx] = f2bf(s);
}

// ============================================================================
// Main GEMM — LDS for A ONLY (ring-4, 64 KiB), B-frags direct from L2 via the
// pre-tiled wbt layout. 256x256 tile, BK=32, 8 waves (2Mx4N), 16x16x32 MFMA,
// read-ahead-1 into named register sets, counted vmcnt, 1 barrier/K-tile.
//
// Per K-tile/CU: MFMA 256 (~1242 cyc) | LDS 64 ds_read_b128 + 16 KiB writes
// (~830 cyc) | vmem 48 KiB from L2 (~340 cyc, overlapped) -> MFMA-bound.
//
// vmcnt audit (issue order per tile: [stage A(t+3) x2][Bload(t+1) x4]):
//   steady entry queue [A(t+2)2, B(t)4]; after issue 12; B(t) done -> vmcnt(6)
//   t=125/126 -> vmcnt(4); t=127 -> vmcnt(0). A(t+1) completion guaranteed by
//   t-1's vmcnt (pops it) + end-of-(t-1) barrier before body-t ds_reads.
// LDS slots: body t reads slot (t+1)&3, writes (t+3)&3 — disjoint; barrier
// spacing bounds wave drift to < 1 K-tile.
// A-swizzle (64B rows, 4x16B slots): slot ^= (row>>1)&3 -> per b128 read all
// 64 lanes touch each 16B slot of a 1KB region exactly once = conflict-free.
// Grid: one W col-panel per XCD (2 MiB < 4 MiB L2) -> B-frag loads L2-hit.
// ============================================================================

__device__ __forceinline__ bf16x8 fragA(const char* slot, int row, int lk) {
    int rb = (row << 6) + ((lk ^ ((row >> 1) & 3)) << 4);
    return *(const bf16x8*)(slot + rb);
}

#define STAGE_A(T_)                                                            \
  { char* dst_ = ldsA + ((T_) & 3) * 16384;                                    \
    int k0_ = (T_) * 32;                                                       \
    { int tb = tid * 16;                                                       \
      int lrow = tb >> 6;                                                      \
      int cb = (tb & 63) ^ ((((lrow) >> 1) & 3) << 4);                         \
      gload_lds16(xrow + (size_t)lrow * DIN + k0_ + (cb >> 1), dst_ + tb); }   \
    { int tb = 8192 + tid * 16;                                                \
      int lrow = tb >> 6;                                                      \
      int cb = (tb & 63) ^ ((((lrow) >> 1) & 3) << 4);                         \
      gload_lds16(xrow + (size_t)lrow * DIN + k0_ + (cb >> 1), dst_ + tb); } }

#define BLOAD(BR_, KT_)                                                        \
    for (int n = 0; n < 4; ++n)                                                \
        BR_[n] = *(const bf16x8*)(wbt +                                        \
            (((size_t)(ctb + n) * 128 + (KT_)) << 9) + l15 * 32 + lk * 8);

#define LDSREAD(AR_, T_)                                                       \
  { const char* slot_ = ldsA + ((T_) & 3) * 16384;                             \
    for (int m = 0; m < 8; ++m)                                                \
        AR_[m] = fragA(slot_, wrow + m * 16 + l15, lk); }

#define VMW(N_)                                                                \
    if ((N_) == 6)      asm volatile("s_waitcnt vmcnt(6)" ::: "memory");       \
    else if ((N_) == 4) asm volatile("s_waitcnt vmcnt(4)" ::: "memory");       \
    else if ((N_) == 0) asm volatile("s_waitcnt vmcnt(0)" ::: "memory");

// MFMA on (AU_,BU_) read last iter; read (AR_,BR_) for tile T_+1 this iter.
#define ITER(AU_, BU_, AR_, BR_, T_, STG_, RD_, VM_, BAR_)                     \
  {                                                                            \
    if (STG_) STAGE_A((T_) + 3);                                               \
    __builtin_amdgcn_sched_barrier(0);                                         \
    if (RD_) { BLOAD(BR_, (T_) + 1); LDSREAD(AR_, (T_) + 1); }                 \
    __builtin_amdgcn_sched_barrier(0);                                         \
    VMW(VM_);                                                                  \
    __builtin_amdgcn_s_setprio(1);                                             \
    for (int m = 0; m < 8; ++m)                                                \
        for (int n = 0; n < 4; ++n)                                            \
            acc[m][n] = __builtin_amdgcn_mfma_f32_16x16x32_bf16(               \
                AU_[m], BU_[n], acc[m][n], 0, 0, 0);                           \
    __builtin_amdgcn_s_setprio(0);                                             \
    if (BAR_) __builtin_amdgcn_s_barrier();                                    \
  }

__global__ __launch_bounds__(512, 2) void main_gemm_kernel(
    const unsigned short* __restrict__ xb, const unsigned short* __restrict__ wbt,
    const unsigned short* __restrict__ ub, const unsigned short* __restrict__ bt,
    const float* __restrict__ bias, const int* __restrict__ cu,
    float* __restrict__ out) {
    __shared__ __attribute__((aligned(1024))) char ldsA[65536];
    int tid  = threadIdx.x;
    int w    = tid >> 6, lane = tid & 63;
    int l15  = lane & 15, lk = lane >> 4;
    int wrow = (w >> 2) * 128;          // wave M-offset in tile
    int wcol = (w & 3) * 64;            // wave N-offset in tile
    // grid: one W col-panel per XCD (L2-resident B)
    int xcd  = blockIdx.x & 7, local = blockIdx.x >> 3;
    int colp = xcd + 8 * (local >> 5);  // 0..15
    int rowp = local & 31;              // 0..31
    int row0 = rowp * 256, col0 = colp * 256;
    int ctb  = colp * 16 + (w & 3) * 4; // wave's first B col-tile

    const unsigned short* xrow = xb + (size_t)row0 * DIN;

    f32x4 acc[8][4] = {};
    bf16x8 afA[8], afB[8], bfA[4], bfB[4];

    // prologue: stage A tiles 0-2, load B(0), drain, read A(0) frags
    STAGE_A(0); STAGE_A(1); STAGE_A(2);
    __builtin_amdgcn_sched_barrier(0);
    BLOAD(bfA, 0);
    asm volatile("s_waitcnt vmcnt(0)" ::: "memory");
    __builtin_amdgcn_s_barrier();
    LDSREAD(afA, 0);

    // main loop: 128 K-tiles of 32
    #pragma unroll 1
    for (int t = 0; t < 124; t += 2) {
        ITER(afA, bfA, afB, bfB, t,     1, 1, 6, 1);
        ITER(afB, bfB, afA, bfA, t + 1, 1, 1, 6, 1);
    }
    ITER(afA, bfA, afB, bfB, 124, 1, 1, 6, 1);   // stages A(127)
    ITER(afB, bfB, afA, bfA, 125, 0, 1, 4, 1);
    ITER(afA, bfA, afB, bfB, 126, 0, 1, 4, 1);
    ITER(afB, bfB, afA, bfA, 127, 0, 0, 0, 0);

    // fused LoRA up-projection: one extra K=32 MFMA step per overlapping segment
    bf16x8 zero = {};
    for (int s = 0; s < NSEG; ++s) {
        int lo = cu[s], hi = cu[s + 1];
        if (hi <= row0 || lo >= row0 + 256) continue;
        bf16x8 au[8], bu[4];
        for (int m = 0; m < 8; ++m) {
            int row = row0 + wrow + m * 16 + l15;
            bf16x8 v = *(const bf16x8*)(ub + (size_t)row * 32 + lk * 8);
            au[m] = (row >= lo && row < hi) ? v : zero;
        }
        for (int n = 0; n < 4; ++n) {
            int col = col0 + wcol + n * 16 + l15;
            bu[n] = *(const bf16x8*)(bt + ((size_t)s * DOUT + col) * 32 + lk * 8);
        }
        for (int m = 0; m < 8; ++m)
            for (int n = 0; n < 4; ++n)
                acc[m][n] = __builtin_amdgcn_mfma_f32_16x16x32_bf16(
                    au[m], bu[n], acc[m][n], 0, 0, 0);
    }

    // epilogue: + bias, fp32 store
    float bv[4];
    for (int n = 0; n < 4; ++n) bv[n] = bias[col0 + wcol + n * 16 + l15];
    for (int m = 0; m < 8; ++m) {
        int rbase = row0 + wrow + m * 16 + lk * 4;
        for (int n = 0; n < 4; ++n) {
            int col = col0 + wcol + n * 16 + l15;
            for (int jj = 0; jj < 4; ++jj)
                out[(size_t)(rbase + jj) * DOUT + col] = acc[m][n][jj] + bv[n];
        }
    }
}

extern "C" void kernel_launch(void* const* d_in, const int* in_sizes, int n_in,
                              void* d_out, int out_size, void* d_ws, size_t ws_size,
                              hipStream_t stream) {
    const float* x  = (const float*)d_in[0];
    const float* W  = (const float*)d_in[1];
    const float* b  = (const float*)d_in[2];
    const float* lA = (const float*)d_in[3];
    const float* lB = (const float*)d_in[4];
    const int*   cu = (const int*)d_in[5];
    float* out = (float*)d_out;

    char* ws = (char*)d_ws;
    unsigned short* xb  = (unsigned short*)(ws);                   // 64 MiB
    unsigned short* wbt = (unsigned short*)(ws + 67108864);        // 32 MiB (tiled)
    unsigned short* At  = (unsigned short*)(ws + 100663296);       // 2 MiB
    unsigned short* Bt  = (unsigned short*)(ws + 102760448);       // 2 MiB
    float*          Pu  = (float*)(ws + 104857600);                // 4 MiB
    unsigned short* ub  = (unsigned short*)(ws + 109051904);       // 0.5 MiB

    const int n8x = T_TOK * DIN / 8, n8w = DOUT * DIN / 8;
    cast2_bf16_kernel<<<(n8x + n8w) / 256, 256, 0, stream>>>(x, xb, n8x, W, wbt, n8w);
    prep_A_kernel<<<(NSEG * 32 * DIN) / 256, 256, 0, stream>>>(lA, At);
    prep_B_kernel<<<(NSEG * DOUT) / 256, 256, 0, stream>>>(lB, Bt);
    dim3 ug(T_TOK / 32, 4);
    u_gemm_kernel<<<ug, 64, 0, stream>>>(xb, At, cu, Pu);
    reduce_u_kernel<<<(T_TOK * 32) / 256, 256, 0, stream>>>(Pu, ub);
    dim3 mg(32 * 16);   // 512 tiles of 256x256
    main_gemm_kernel<<<mg, 512, 0, stream>>>(xb, wbt, ub, Bt, b, cu, out);
}

// Round 10
// 351.789 us; speedup vs baseline: 1.1059x; 1.1059x over previous
//
#include <hip/hip_runtime.h>
#include <hip/hip_bf16.h>

// Problem constants (BLoraLinear): T=8192, D_IN=4096, D_OUT=4096, R=16, M=2, S=8
#define T_TOK 8192
#define DIN   4096
#define DOUT  4096
#define RANK  16
#define NMOD  2
#define NSEG  8

typedef __attribute__((ext_vector_type(8))) short bf16x8;
typedef __attribute__((ext_vector_type(8))) unsigned short u16x8;
typedef __attribute__((ext_vector_type(4))) float f32x4;

__device__ inline unsigned short f2bf(float f) {
    union { float f; unsigned u; } v; v.f = f;
    unsigned r = v.u + 0x7FFFu + ((v.u >> 16) & 1u);   // RNE
    return (unsigned short)(r >> 16);
}

__device__ inline void gload_lds16(const void* g, void* l) {
    __builtin_amdgcn_global_load_lds(
        (const __attribute__((address_space(1))) void*)g,
        (__attribute__((address_space(3))) void*)l, 16, 0, 0);
}

// ---------------- fp32 -> bf16 cast for x and W in one launch ----------------
__global__ void cast2_bf16_kernel(const float* __restrict__ sa,
                                  unsigned short* __restrict__ da, int n8a,
                                  const float* __restrict__ sb,
                                  unsigned short* __restrict__ db, int n8b) {
    int i = blockIdx.x * blockDim.x + threadIdx.x;
    const float* s;
    unsigned short* d;
    size_t j;
    if (i < n8a) { s = sa; d = da; j = (size_t)i; }
    else if (i < n8a + n8b) { s = sb; d = db; j = (size_t)(i - n8a); }
    else return;
    const float4* s4 = (const float4*)s;
    float4 a = s4[2 * j];
    float4 b = s4[2 * j + 1];
    u16x8 o;
    o[0] = f2bf(a.x); o[1] = f2bf(a.y); o[2] = f2bf(a.z); o[3] = f2bf(a.w);
    o[4] = f2bf(b.x); o[5] = f2bf(b.y); o[6] = f2bf(b.z); o[7] = f2bf(b.w);
    *(u16x8*)(d + 8 * j) = o;
}

// ---------- At[s][m*16+r][d] = lora_A[m][s][d][r]  (bf16) --------------------
__global__ void prep_A_kernel(const float* __restrict__ A,
                              unsigned short* __restrict__ At) {
    int idx = blockIdx.x * 256 + threadIdx.x;     // NSEG*32*DIN total
    int d   = idx & (DIN - 1);
    int smr = idx >> 12;
    int s   = smr >> 5, mr = smr & 31;
    int m   = mr >> 4,  r  = mr & 15;
    float v = A[(((size_t)(m * NSEG + s) * DIN) + d) * RANK + r];
    At[idx] = f2bf(v);
}

// ---------- Bt[s][o][m*16+r] = lora_B[m][s][r][o]  (bf16) --------------------
__global__ void prep_B_kernel(const float* __restrict__ B,
                              unsigned short* __restrict__ Bt) {
    int o  = blockIdx.x * 256 + threadIdx.x;      // NSEG*DOUT total
    int s  = o >> 12;
    int oc = o & (DOUT - 1);
    unsigned short tmp[32];
    for (int m = 0; m < NMOD; ++m)
        for (int r = 0; r < RANK; ++r)
            tmp[m * 16 + r] =
                f2bf(B[(((size_t)(m * NSEG + s) * RANK) + r) * DOUT + oc]);
    for (int k = 0; k < 4; ++k) {
        u16x8 v;
        for (int j = 0; j < 8; ++j) v[j] = tmp[k * 8 + j];
        *(u16x8*)(Bt + (size_t)o * 32 + k * 8) = v;
    }
}

// ---------- u partials: Pu[ky][t][mr] = sum_{k in split} x[t,k]*At[s(t)][mr][k]
__global__ __launch_bounds__(64) void u_gemm_kernel(
    const unsigned short* __restrict__ xb, const unsigned short* __restrict__ At,
    const int* __restrict__ cu, float* __restrict__ Pu) {
    int tile = blockIdx.x;          // 0..255
    int ky   = blockIdx.y;          // 0..3
    int lane = threadIdx.x;
    int l15  = lane & 15, lk = lane >> 4;
    int t0   = tile * 32;
    f32x4 acc[2][2] = {};
    bf16x8 zero = {};
    for (int s = 0; s < NSEG; ++s) {
        int lo = cu[s], hi = cu[s + 1];
        if (hi <= t0 || lo >= t0 + 32) continue;
        const unsigned short* atb = At + (size_t)(s * 32) * DIN;
        for (int kt = 0; kt < 32; ++kt) {
            int k0 = ky * 1024 + kt * 32 + lk * 8;
            bf16x8 a[2], b[2];
            for (int mi = 0; mi < 2; ++mi) {
                int row = t0 + mi * 16 + l15;
                bf16x8 av = *(const bf16x8*)(xb + (size_t)row * DIN + k0);
                a[mi] = (row >= lo && row < hi) ? av : zero;
            }
            for (int ni = 0; ni < 2; ++ni) {
                int mr = ni * 16 + l15;
                b[ni] = *(const bf16x8*)(atb + (size_t)mr * DIN + k0);
            }
            for (int mi = 0; mi < 2; ++mi)
                for (int ni = 0; ni < 2; ++ni)
                    acc[mi][ni] = __builtin_amdgcn_mfma_f32_16x16x32_bf16(
                        a[mi], b[ni], acc[mi][ni], 0, 0, 0);
        }
    }
    for (int mi = 0; mi < 2; ++mi)
        for (int ni = 0; ni < 2; ++ni)
            for (int j = 0; j < 4; ++j) {
                int t  = t0 + mi * 16 + lk * 4 + j;
                int mr = ni * 16 + l15;
                Pu[((size_t)ky * T_TOK + t) * 32 + mr] = acc[mi][ni][j];
            }
}

// ---------- reduce 4 K-split partials -> ub bf16 [T][32] ---------------------
__global__ void reduce_u_kernel(const float* __restrict__ Pu,
                                unsigned short* __restrict__ ub) {
    int idx = blockIdx.x * 256 + threadIdx.x;   // T_TOK*32
    const size_t STRIDE = (size_t)T_TOK * 32;
    float s = Pu[idx] + Pu[idx + STRIDE] + Pu[idx + 2 * STRIDE] + Pu[idx + 3 * STRIDE];
    ub[idx] = f2bf(s);
}

// ============================================================================
// Main GEMM — 2-blocks/CU cross-overlap. 128x256 tile, BK=32, 4 waves (1Mx4N),
// ring-3 LDS (3 x 24 KiB = 72 KiB -> 2 blocks/CU), 16x16x32 MFMA.
//
// Mechanism: two INDEPENDENT barrier domains per CU. Block A's MFMA clusters
// overlap block B's ds_read/stage phases on the CU's separate pipes (m114
// co-schedule) -> per-CU time -> max(MFMA, LDS) instead of sum. Intra-block
// schedule = R6's proven dual-barrier phase:
//   { ds_reads ; stage gloads ; [vmcnt(6) at ph1] ; s_barrier ; lgkmcnt(0) ;
//     sched_barrier(0) ; setprio(1) ; 16 MFMA ; setprio(0) ; s_barrier }
// 2 phases per K-tile-32 (acc[0-3] / acc[4-7]).
//
// Ring-3 audit: body t reads slot t%3, stages tile t+2 into slot (t+2)%3;
// tile t+1 in slot (t+1)%3 untouched. vmcnt(6) at ph1 pops tile-(t+1)'s 6
// loads (issued body t-1, ~2 K-tiles ago >= 2500 cyc >> 900 HBM latency).
// Stage = 6 gloads/thread/K-tile (A 2 + B 4; 256 threads x 16 B).
// Swizzle (64B rows, verified 0-conflict in R9): slot16 ^= (row>>1)&3 applied
// to global SOURCE (linear LDS dest) and ds_read addr; 16 rows/frag-read ->
// 2 lanes/bank = free.
// XCD: swz=(bid&7)*128+bid>>3 -> each XCD owns 2 contiguous col-panels
// (B-panel 2x2 MiB = L2-resident).
// ============================================================================

__device__ __forceinline__ bf16x8 fragA(const char* mat, int row, int lk) {
    int rb = (row << 6) + ((lk ^ ((row >> 1) & 3)) << 4);
    return *(const bf16x8*)(mat + rb);
}

// stage 4 KiB round: 256 threads x 16 B; rows TB>>6; pre-swizzled source
#define STAGE_R(GB_, LD_, TB_, K0_)                                           \
  { int tb = (TB_);                                                            \
    int lrow = tb >> 6;                                                        \
    int cb = (tb & 63) ^ (((lrow >> 1) & 3) << 4);                             \
    gload_lds16((GB_) + (size_t)lrow * DIN + (K0_) + (cb >> 1), (LD_) + tb); }

#define MFMA16(B0_, AF_)                                                       \
    __builtin_amdgcn_s_setprio(1);                                             \
    for (int m = 0; m < 4; ++m)                                                \
        for (int n = 0; n < 4; ++n)                                            \
            acc[(B0_) + m][n] = __builtin_amdgcn_mfma_f32_16x16x32_bf16(       \
                AF_[m], bf[n], acc[(B0_) + m][n], 0, 0, 0);                    \
    __builtin_amdgcn_s_setprio(0);

#define PH_MID()                                                               \
    __builtin_amdgcn_s_barrier();                                              \
    asm volatile("s_waitcnt lgkmcnt(0)" ::: "memory");                         \
    __builtin_amdgcn_sched_barrier(0);

// SR_: read slot 0..2; SS_: stage slot; STG_: stage tile T_+2; VM_: 6/0/-1
#define BODY(T_, SR_, SS_, STG_, VM_)                                          \
  {                                                                            \
    const char* cA = lds + (SR_) * 24576;                                      \
    const char* cB = cA + 8192;                                                \
    char* sA = lds + (SS_) * 24576;                                            \
    char* sB = sA + 8192;                                                      \
    const int k0n = ((T_) + 2) * 32;                                           \
    bf16x8 bf[4], af[4];                                                       \
    /* ---- ph0: MFMA acc[0-3] ---- */                                         \
    for (int n = 0; n < 4; ++n) bf[n] = fragA(cB, wcol + n*16 + l15, lk);      \
    for (int m = 0; m < 4; ++m) af[m] = fragA(cA, m*16 + l15, lk);             \
    if (STG_) { STAGE_R(xrow, sA, tid*16, k0n);                                \
                STAGE_R(xrow, sA, 4096 + tid*16, k0n);                         \
                STAGE_R(wrow_g, sB, tid*16, k0n); }                            \
    PH_MID();                                                                  \
    MFMA16(0, af);                                                             \
    __builtin_amdgcn_s_barrier();                                              \
    /* ---- ph1: MFMA acc[4-7] ---- */                                         \
    for (int m = 0; m < 4; ++m) af[m] = fragA(cA, 64 + m*16 + l15, lk);        \
    if (STG_) { STAGE_R(wrow_g, sB, 4096 + tid*16, k0n);                       \
                STAGE_R(wrow_g, sB, 8192 + tid*16, k0n);                       \
                STAGE_R(wrow_g, sB, 12288 + tid*16, k0n); }                    \
    if ((VM_) == 6)      asm volatile("s_waitcnt vmcnt(6)" ::: "memory");      \
    else if ((VM_) == 0) asm volatile("s_waitcnt vmcnt(0)" ::: "memory");      \
    PH_MID();                                                                  \
    MFMA16(4, af);                                                             \
    __builtin_amdgcn_s_barrier();                                              \
  }

__global__ __launch_bounds__(256, 2) void main_gemm_kernel(
    const unsigned short* __restrict__ xb, const unsigned short* __restrict__ wb,
    const unsigned short* __restrict__ ub, const unsigned short* __restrict__ bt,
    const float* __restrict__ bias, const int* __restrict__ cu,
    float* __restrict__ out) {
    __shared__ __attribute__((aligned(1024))) char lds[73728];  // 3 x 24 KiB
    int tid  = threadIdx.x;
    int w    = tid >> 6, lane = tid & 63;
    int l15  = lane & 15, lk = lane >> 4;
    int wcol = w * 64;                   // wave N-offset in 256-wide tile
    // XCD swizzle: 1024 blocks; XCD x owns 128 contiguous swz = 2 col-panels
    int swz  = (blockIdx.x & 7) * 128 + (blockIdx.x >> 3);
    int colp = swz >> 6;                 // 0..15
    int rowp = swz & 63;                 // 0..63
    int row0 = rowp * 128, col0 = colp * 256;

    const unsigned short* xrow   = xb + (size_t)row0 * DIN;
    const unsigned short* wrow_g = wb + (size_t)col0 * DIN;

    f32x4 acc[8][4] = {};

    // prologue: stage tiles 0 (slot0) and 1 (slot1); vmcnt(6) -> tile 0 done
    {
        char* sA = lds;          char* sB = lds + 8192;
        STAGE_R(xrow, sA, tid*16, 0);  STAGE_R(xrow, sA, 4096 + tid*16, 0);
        STAGE_R(wrow_g, sB, tid*16, 0); STAGE_R(wrow_g, sB, 4096 + tid*16, 0);
        STAGE_R(wrow_g, sB, 8192 + tid*16, 0); STAGE_R(wrow_g, sB, 12288 + tid*16, 0);
        sA = lds + 24576;        sB = sA + 8192;
        STAGE_R(xrow, sA, tid*16, 32); STAGE_R(xrow, sA, 4096 + tid*16, 32);
        STAGE_R(wrow_g, sB, tid*16, 32); STAGE_R(wrow_g, sB, 4096 + tid*16, 32);
        STAGE_R(wrow_g, sB, 8192 + tid*16, 32); STAGE_R(wrow_g, sB, 12288 + tid*16, 32);
    }
    asm volatile("s_waitcnt vmcnt(6)" ::: "memory");
    __builtin_amdgcn_s_barrier();

    // main loop: 128 K-tiles of 32; unroll x3 for static ring-3 slots
    #pragma unroll 1
    for (int t = 0; t < 126; t += 3) {
        BODY(t,     0, 2, 1, 6);
        BODY(t + 1, 1, 0, 1, 6);
        BODY(t + 2, 2, 1, 1, 6);
    }
    BODY(126, 0, 2, 0, 0);   // vmcnt(0): tile 127 (staged body 125) landed
    BODY(127, 1, 2, 0, -1);

    // fused LoRA up-projection: one extra K=32 MFMA step per overlapping segment
    bf16x8 zero = {};
    for (int s = 0; s < NSEG; ++s) {
        int lo = cu[s], hi = cu[s + 1];
        if (hi <= row0 || lo >= row0 + 128) continue;
        bf16x8 au[8], bu[4];
        for (int m = 0; m < 8; ++m) {
            int row = row0 + m * 16 + l15;
            bf16x8 v = *(const bf16x8*)(ub + (size_t)row * 32 + lk * 8);
            au[m] = (row >= lo && row < hi) ? v : zero;
        }
        for (int n = 0; n < 4; ++n) {
            int col = col0 + wcol + n * 16 + l15;
            bu[n] = *(const bf16x8*)(bt + ((size_t)s * DOUT + col) * 32 + lk * 8);
        }
        for (int m = 0; m < 8; ++m)
            for (int n = 0; n < 4; ++n)
                acc[m][n] = __builtin_amdgcn_mfma_f32_16x16x32_bf16(
                    au[m], bu[n], acc[m][n], 0, 0, 0);
    }

    // epilogue: + bias, fp32 store
    float bv[4];
    for (int n = 0; n < 4; ++n) bv[n] = bias[col0 + wcol + n * 16 + l15];
    for (int m = 0; m < 8; ++m) {
        int rbase = row0 + m * 16 + lk * 4;
        for (int n = 0; n < 4; ++n) {
            int col = col0 + wcol + n * 16 + l15;
            for (int jj = 0; jj < 4; ++jj)
                out[(size_t)(rbase + jj) * DOUT + col] = acc[m][n][jj] + bv[n];
        }
    }
}

extern "C" void kernel_launch(void* const* d_in, const int* in_sizes, int n_in,
                              void* d_out, int out_size, void* d_ws, size_t ws_size,
                              hipStream_t stream) {
    const float* x  = (const float*)d_in[0];
    const float* W  = (const float*)d_in[1];
    const float* b  = (const float*)d_in[2];
    const float* lA = (const float*)d_in[3];
    const float* lB = (const float*)d_in[4];
    const int*   cu = (const int*)d_in[5];
    float* out = (float*)d_out;

    char* ws = (char*)d_ws;
    unsigned short* xb = (unsigned short*)(ws);                    // 64 MiB
    unsigned short* wb = (unsigned short*)(ws + 67108864);         // 32 MiB
    unsigned short* At = (unsigned short*)(ws + 100663296);        // 2 MiB
    unsigned short* Bt = (unsigned short*)(ws + 102760448);        // 2 MiB
    float*          Pu = (float*)(ws + 104857600);                 // 4 MiB
    unsigned short* ub = (unsigned short*)(ws + 109051904);        // 0.5 MiB

    const int n8x = T_TOK * DIN / 8, n8w = DOUT * DIN / 8;
    cast2_bf16_kernel<<<(n8x + n8w) / 256, 256, 0, stream>>>(x, xb, n8x, W, wb, n8w);
    prep_A_kernel<<<(NSEG * 32 * DIN) / 256, 256, 0, stream>>>(lA, At);
    prep_B_kernel<<<(NSEG * DOUT) / 256, 256, 0, stream>>>(lB, Bt);
    dim3 ug(T_TOK / 32, 4);
    u_gemm_kernel<<<ug, 64, 0, stream>>>(xb, At, cu, Pu);
    reduce_u_kernel<<<(T_TOK * 32) / 256, 256, 0, stream>>>(Pu, ub);
    dim3 mg(64 * 16);   // 1024 tiles of 128x256
    main_gemm_kernel<<<mg, 256, 0, stream>>>(xb, wb, ub, Bt, b, cu, out);
}